// Round 1
// baseline (150.404 us; speedup 1.0000x reference)
//
#include <hip/hip_runtime.h>

#define N_  8
#define D_  64
#define H_  64
#define W_  64
#define HW_ (H_ * W_)
#define KK  25

// ---------------------------------------------------------------------------
// Kernel 1: per-batch nonzero counts of cur and prev.
// Each block covers 256*4 = 1024 contiguous elements -> always within one n
// (D*HW = 262144 is divisible by 1024). cnt[0..7] = cur, cnt[8..15] = prev.
// ---------------------------------------------------------------------------
__global__ __launch_bounds__(256) void count_nz_kernel(
    const float4* __restrict__ cur, const float4* __restrict__ prev,
    unsigned int* __restrict__ cnt)
{
    __shared__ unsigned int sc, sp;
    if (threadIdx.x == 0) { sc = 0u; sp = 0u; }
    __syncthreads();

    int i = blockIdx.x * blockDim.x + threadIdx.x;
    float4 a = cur[i];
    float4 b = prev[i];
    unsigned int ca = (a.x != 0.f) + (a.y != 0.f) + (a.z != 0.f) + (a.w != 0.f);
    unsigned int cb = (b.x != 0.f) + (b.y != 0.f) + (b.z != 0.f) + (b.w != 0.f);
    atomicAdd(&sc, ca);
    atomicAdd(&sp, cb);
    __syncthreads();

    if (threadIdx.x == 0) {
        int n = (int)(((size_t)blockIdx.x * blockDim.x * 4) / (D_ * HW_));
        atomicAdd(&cnt[n],     sc);
        atomicAdd(&cnt[8 + n], sp);
    }
}

// ---------------------------------------------------------------------------
// Kernel 2: main fused FeatureAlign. One thread per (n, pixel).
// Computes 25 window dot-products over D, scales by 1/(nc*npv), relu,
// normalizes by mass, then gathers prev_mem (or copies it on zero mass).
// ---------------------------------------------------------------------------
__global__ __launch_bounds__(256) void feature_align_kernel(
    const float* __restrict__ cur, const float* __restrict__ prev,
    const float* __restrict__ pm, float* __restrict__ out,
    const unsigned int* __restrict__ cnt)
{
    int t = blockIdx.x * blockDim.x + threadIdx.x;   // 0 .. N*HW-1
    int p = t & (HW_ - 1);
    int n = t >> 12;                                  // HW = 4096
    int y = p >> 6;                                   // W  = 64
    int x = p & 63;

    float ncf = (float)cnt[n]     + 1e-8f;
    float npf = (float)cnt[8 + n] + 1e-8f;
    float scale = 1.0f / (ncf * npf);

    // Precompute clamped window offsets (relative to p) and validity.
    int  off[KK];
    bool valid[KK];
#pragma unroll
    for (int ky = 0; ky < 5; ++ky) {
#pragma unroll
        for (int kx = 0; kx < 5; ++kx) {
            int py = y + ky - 2;
            int px = x + kx - 2;
            bool v = (py >= 0) && (py < H_) && (px >= 0) && (px < W_);
            int cy = min(max(py, 0), H_ - 1);
            int cx = min(max(px, 0), W_ - 1);
            valid[ky * 5 + kx] = v;
            off[ky * 5 + kx]   = cy * W_ + cx - p;
        }
    }

    const float* curp  = cur  + (size_t)n * D_ * HW_ + p;
    const float* prevp = prev + (size_t)n * D_ * HW_ + p;

    float acc[KK];
#pragma unroll
    for (int k = 0; k < KK; ++k) acc[k] = 0.f;

    // 25 window dot-products over D. cur load coalesced; each of the 25
    // prev loads is a coalesced shifted stream (L1-resident reuse).
    for (int d = 0; d < D_; ++d) {
        float c = curp[(size_t)d * HW_];
        const float* pp = prevp + (size_t)d * HW_;
#pragma unroll
        for (int k = 0; k < KK; ++k)
            acc[k] = fmaf(c, pp[off[k]], acc[k]);
    }

    // Scale, relu, mask invalid, accumulate mass.
    float mass = 0.f;
#pragma unroll
    for (int k = 0; k < KK; ++k) {
        float cf = valid[k] ? fmaxf(acc[k] * scale, 0.f) : 0.f;
        acc[k] = cf;
        mass  += cf;
    }

    bool zero = fabsf(mass) < 1e-7f;

    const float* pmp  = pm  + (size_t)n * D_ * HW_ + p;
    float*       outp = out + (size_t)n * D_ * HW_ + p;

    if (zero) {
        for (int d = 0; d < D_; ++d)
            outp[(size_t)d * HW_] = pmp[(size_t)d * HW_];
    } else {
        float inv = 1.0f / mass;
#pragma unroll
        for (int k = 0; k < KK; ++k) acc[k] *= inv;
        for (int d = 0; d < D_; ++d) {
            const float* pp = pmp + (size_t)d * HW_;
            float v = 0.f;
#pragma unroll
            for (int k = 0; k < KK; ++k)
                v = fmaf(acc[k], pp[off[k]], v);
            outp[(size_t)d * HW_] = v;
        }
    }
}

extern "C" void kernel_launch(void* const* d_in, const int* in_sizes, int n_in,
                              void* d_out, int out_size, void* d_ws, size_t ws_size,
                              hipStream_t stream)
{
    const float* cur  = (const float*)d_in[0];
    const float* prev = (const float*)d_in[1];
    const float* pm   = (const float*)d_in[2];
    float*       out  = (float*)d_out;
    unsigned int* cnt = (unsigned int*)d_ws;

    // ws is re-poisoned to 0xAA before every timed launch -> zero the counters.
    hipMemsetAsync(cnt, 0, 16 * sizeof(unsigned int), stream);

    int total_vec4 = N_ * D_ * HW_ / 4;               // 524288
    count_nz_kernel<<<total_vec4 / 256, 256, 0, stream>>>(
        (const float4*)cur, (const float4*)prev, cnt);

    int total_pix = N_ * HW_;                         // 32768
    feature_align_kernel<<<total_pix / 256, 256, 0, stream>>>(
        cur, prev, pm, out, cnt);
}

// Round 2
// 100.020 us; speedup vs baseline: 1.5037x; 1.5037x over previous
//
#include <hip/hip_runtime.h>

#define N_  8
#define D_  64
#define H_  64
#define W_  64
#define HW_ (H_ * W_)
#define KK  25

// ---------------------------------------------------------------------------
// Kernel 1: per-batch nonzero counts of cur and prev.
// 512 blocks x 256 threads; each thread handles 4 float4 (16 KB/block).
// Wave-level ballot+popcount (no serialized atomics), one LDS slot per wave,
// one global atomic per block per array. Block always within one n
// (1024 float4 per block, 65536 float4 per n).
// cnt[0..7] = cur counts, cnt[8..15] = prev counts.
// ---------------------------------------------------------------------------
__global__ __launch_bounds__(256) void count_nz_kernel(
    const float4* __restrict__ cur, const float4* __restrict__ prev,
    unsigned int* __restrict__ cnt)
{
    __shared__ unsigned int sc[4], sp[4];
    const int t    = threadIdx.x;
    const int wid  = t >> 6;
    const int lane = t & 63;

    unsigned int wc = 0, wp = 0;
#pragma unroll
    for (int j = 0; j < 4; ++j) {
        int idx = blockIdx.x * 1024 + j * 256 + t;
        float4 a = cur[idx];
        float4 b = prev[idx];
        wc += (unsigned)__popcll(__ballot(a.x != 0.f));
        wc += (unsigned)__popcll(__ballot(a.y != 0.f));
        wc += (unsigned)__popcll(__ballot(a.z != 0.f));
        wc += (unsigned)__popcll(__ballot(a.w != 0.f));
        wp += (unsigned)__popcll(__ballot(b.x != 0.f));
        wp += (unsigned)__popcll(__ballot(b.y != 0.f));
        wp += (unsigned)__popcll(__ballot(b.z != 0.f));
        wp += (unsigned)__popcll(__ballot(b.w != 0.f));
    }
    if (lane == 0) { sc[wid] = wc; sp[wid] = wp; }
    __syncthreads();

    if (t == 0) {
        int n = blockIdx.x >> 6;     // 64 blocks per batch
        atomicAdd(&cnt[n],     sc[0] + sc[1] + sc[2] + sc[3]);
        atomicAdd(&cnt[8 + n], sp[0] + sp[1] + sp[2] + sp[3]);
    }
}

// ---------------------------------------------------------------------------
// Kernel 2: fused FeatureAlign. Block = (n, y): 512 blocks, 256 threads =
// 64 x-lanes x 4 d-groups. Each d-group accumulates the 25 window dots over
// its 16 channels; partials reduced across groups through LDS.
// ---------------------------------------------------------------------------
__global__ __launch_bounds__(256) void feature_align_kernel(
    const float* __restrict__ cur, const float* __restrict__ prev,
    const float* __restrict__ pm, float* __restrict__ out,
    const unsigned int* __restrict__ cnt)
{
    __shared__ float red[4][KK][64];    // 25.6 KB  partial dots
    __shared__ float wght[KK][64];      //  6.4 KB  normalized weights
    __shared__ int   zflag[64];

    const int nb = blockIdx.x;          // 0..511
    const int n  = nb >> 6;
    const int y  = nb & 63;
    const int x  = threadIdx.x & 63;
    const int dg = threadIdx.x >> 6;
    const int p  = y * W_ + x;

    // Window offsets (relative, clamped) + validity.
    int  off[KK];
    bool valid[KK];
#pragma unroll
    for (int ky = 0; ky < 5; ++ky) {
#pragma unroll
        for (int kx = 0; kx < 5; ++kx) {
            int py = y + ky - 2;
            int px = x + kx - 2;
            valid[ky * 5 + kx] = (py >= 0) && (py < H_) && (px >= 0) && (px < W_);
            int cy = min(max(py, 0), H_ - 1);
            int cx = min(max(px, 0), W_ - 1);
            off[ky * 5 + kx] = cy * W_ + cx - p;
        }
    }

    const size_t nbase = (size_t)n * D_ * HW_ + p;
    const float* curp  = cur  + nbase;
    const float* prevp = prev + nbase;

    float acc[KK];
#pragma unroll
    for (int k = 0; k < KK; ++k) acc[k] = 0.f;

    // 16 channels per d-group: 25 window dot partials.
    for (int dd = 0; dd < 16; ++dd) {
        int d = dg * 16 + dd;
        float c = curp[(size_t)d * HW_];
        const float* pp = prevp + (size_t)d * HW_;
#pragma unroll
        for (int k = 0; k < KK; ++k)
            acc[k] = fmaf(c, pp[off[k]], acc[k]);
    }

#pragma unroll
    for (int k = 0; k < KK; ++k) red[dg][k][x] = acc[k];
    __syncthreads();

    if (dg == 0) {
        float ncf = (float)cnt[n]     + 1e-8f;
        float npf = (float)cnt[8 + n] + 1e-8f;
        float scale = 1.0f / (ncf * npf);

        float mass = 0.f;
        float cf[KK];
#pragma unroll
        for (int k = 0; k < KK; ++k) {
            float s = red[0][k][x] + red[1][k][x] + red[2][k][x] + red[3][k][x];
            float c = valid[k] ? fmaxf(s * scale, 0.f) : 0.f;
            cf[k] = c;
            mass += c;
        }
        bool zero = fabsf(mass) < 1e-7f;
        float inv = zero ? 0.f : 1.0f / mass;
#pragma unroll
        for (int k = 0; k < KK; ++k) wght[k][x] = cf[k] * inv;
        zflag[x] = zero ? 1 : 0;
    }
    __syncthreads();

    const float* pmp  = pm  + nbase;
    float*       outp = out + nbase;

    if (zflag[x]) {
        // Hot path on this data: straight copy of prev_mem (coalesced).
        for (int dd = 0; dd < 16; ++dd) {
            size_t o = (size_t)(dg * 16 + dd) * HW_;
            outp[o] = pmp[o];
        }
    } else {
        float w[KK];
#pragma unroll
        for (int k = 0; k < KK; ++k) w[k] = wght[k][x];  // invalid k -> 0
        for (int dd = 0; dd < 16; ++dd) {
            size_t o = (size_t)(dg * 16 + dd) * HW_;
            const float* pp = pmp + o;
            float v = 0.f;
#pragma unroll
            for (int k = 0; k < KK; ++k)
                v = fmaf(w[k], pp[off[k]], v);
            outp[o] = v;
        }
    }
}

extern "C" void kernel_launch(void* const* d_in, const int* in_sizes, int n_in,
                              void* d_out, int out_size, void* d_ws, size_t ws_size,
                              hipStream_t stream)
{
    const float* cur  = (const float*)d_in[0];
    const float* prev = (const float*)d_in[1];
    const float* pm   = (const float*)d_in[2];
    float*       out  = (float*)d_out;
    unsigned int* cnt = (unsigned int*)d_ws;

    // ws is re-poisoned to 0xAA before every timed launch -> zero the counters.
    hipMemsetAsync(cnt, 0, 16 * sizeof(unsigned int), stream);

    count_nz_kernel<<<512, 256, 0, stream>>>(
        (const float4*)cur, (const float4*)prev, cnt);

    feature_align_kernel<<<512, 256, 0, stream>>>(cur, prev, pm, out, cnt);
}